// Round 5
// baseline (345.829 us; speedup 1.0000x reference)
//
#include <hip/hip_runtime.h>
#include <hip/hip_bf16.h>

typedef __attribute__((ext_vector_type(8))) short bf16x8;
typedef __attribute__((ext_vector_type(4))) float f32x4;
typedef __attribute__((ext_vector_type(8))) unsigned short u16x8;

#define RR 128
#define CC 256
#define EE 768
#define HH 12
#define DKK 64
#define NQKV 2304

__device__ __forceinline__ unsigned short f2bf(float f) {
  union { float f; unsigned u; } v; v.f = f;
  unsigned u = v.u;
  unsigned r = (u + 0x7fffu + ((u >> 16) & 1u)) >> 16;
  return (unsigned short)r;
}

__device__ __forceinline__ void gload16(const unsigned short* g, char* l) {
  __builtin_amdgcn_global_load_lds((const __attribute__((address_space(1))) void*)g,
                                   (__attribute__((address_space(3))) void*)l, 16, 0, 0);
}

// ---------------- fused cast fp32 -> bf16 (x + 4 weight matrices) -----------
__global__ void cast_all(const float* __restrict__ x, const float* __restrict__ w0,
                         const float* __restrict__ w1, const float* __restrict__ w2,
                         const float* __restrict__ w3, unsigned short* __restrict__ xb,
                         unsigned short* __restrict__ wdst) {
  int b = blockIdx.x;
  const float* src;
  unsigned short* dst;
  int t;
  if (b < 12288) {
    src = x; dst = xb; t = b * 256 + (int)threadIdx.x;
  } else {
    int bb = b - 12288;
    int m = bb / 288;
    src = (m == 0) ? w0 : (m == 1) ? w1 : (m == 2) ? w2 : w3;
    dst = wdst + (size_t)m * 589824;
    t = (bb - m * 288) * 256 + (int)threadIdx.x;
  }
  const float4* s = (const float4*)src + (size_t)t * 2;
  float4 a = s[0], bq = s[1];
  u16x8 o;
  o[0] = f2bf(a.x); o[1] = f2bf(a.y); o[2] = f2bf(a.z); o[3] = f2bf(a.w);
  o[4] = f2bf(bq.x); o[5] = f2bf(bq.y); o[6] = f2bf(bq.z); o[7] = f2bf(bq.w);
  *(u16x8*)(dst + (size_t)t * 8) = o;
}

// ---------------- 256x256 8-phase GEMM: C = A[M][768] * B[N][768]^T (+bias) --
// OUTMODE 1 (QKV): writes bf16 in attention-native layout [c][h][i][d] per
//   matrix (Q scaled by 0.125), via 128KB LDS epilogue.
// OUTMODE 0 (out-proj): A rows are c-major ctx (u = c*128+i); epilogue
//   un-permutes to token-major fp32 out[t*768+col], t = (u&127)<<8 | (u>>7).

#define SBAR() do { __builtin_amdgcn_sched_barrier(0); __builtin_amdgcn_s_barrier(); } while (0)
#define SBAR2() do { __builtin_amdgcn_sched_barrier(0); __builtin_amdgcn_s_barrier(); __builtin_amdgcn_sched_barrier(0); } while (0)
#define WAITL() do { asm volatile("s_waitcnt lgkmcnt(0)" ::: "memory"); __builtin_amdgcn_sched_barrier(0); } while (0)
#define WAITV(N) asm volatile("s_waitcnt vmcnt(" #N ")" ::: "memory")

template <int OUTMODE>
__global__ __launch_bounds__(512, 2) void gemm256(
    const unsigned short* __restrict__ A, const unsigned short* __restrict__ Bw,
    void* __restrict__ OutP, const float* __restrict__ bias0,
    const float* __restrict__ bias1, const float* __restrict__ bias2) {
  __shared__ __align__(16) char smem[131072];
  const int nwg = gridDim.x;
  const int chunk = nwg >> 3;
  const int swz = ((int)blockIdx.x & 7) * chunk + ((int)blockIdx.x >> 3);
  const int bm = swz % 128, bn = swz / 128;
  const int r0 = bm << 8, c0 = bn << 8;

  const int tid = threadIdx.x;
  const int w = tid >> 6, lane = tid & 63;
  const int wr = w >> 2, wc = w & 3;
  const int lr = lane & 15, lg = lane >> 4;
  const int l8 = lane >> 3, l7 = lane & 7;
  const int swzc = (l7 ^ (l8 & 7)) << 3;  // element offset, pre-swizzled source
  const unsigned short* pa = A + (size_t)(r0 + l8) * EE + swzc;
  const unsigned short* pb = Bw + (size_t)(c0 + l8) * EE + swzc;
  const int j0 = w, j1 = w + 8;

  // ds_read byte offsets
  const int aoff = (wr << 14) + (lr << 7);
  const int boff = 32768 + ((wc >> 1) << 14) + ((wc & 1) << 13) + (lr << 7);
  const int sw0 = ((0 + lg) ^ (lr & 7)) << 4;  // kk=0 col16 = lg
  const int sw1 = ((4 + lg) ^ (lr & 7)) << 4;  // kk=1 col16 = 4+lg

  f32x4 acc[8][4] = {};
  bf16x8 aA[4], aB[4], aC[4], aD[4], bA[4], bB[4];

#define STAGE(s, H, t)                                                        \
  do {                                                                        \
    const unsigned short* _src = ((H) < 2 ? pa : pb) +                        \
        (size_t)(((H) & 1) * 128) * EE + (size_t)(t) * 64;                    \
    char* _d = smem + (s) * 65536 + ((H) >= 2 ? 32768 : 0) + ((H) & 1) * 16384; \
    gload16(_src + (size_t)j0 * 8 * EE, _d + j0 * 1024);                      \
    gload16(_src + (size_t)j1 * 8 * EE, _d + j1 * 1024);                      \
  } while (0)

#define RD_A(dst, g, SW, s)                                                   \
  _Pragma("unroll") for (int _m = 0; _m < 4; ++_m)                            \
      dst[_m] = *(const bf16x8*)(smem + (s) * 65536 + aoff + (g) * 8192 +     \
                                 _m * 2048 + (SW));

#define RD_B(dst, SW, s)                                                      \
  _Pragma("unroll") for (int _n = 0; _n < 4; ++_n)                            \
      dst[_n] = *(const bf16x8*)(smem + (s) * 65536 + boff + _n * 2048 + (SW));

#define MM(g, ar, br)                                                         \
  do {                                                                        \
    __builtin_amdgcn_s_setprio(1);                                            \
    _Pragma("unroll") for (int _i = 0; _i < 4; ++_i)                          \
        _Pragma("unroll") for (int _j = 0; _j < 4; ++_j)                      \
            acc[(g) * 4 + _i][_j] = __builtin_amdgcn_mfma_f32_16x16x32_bf16(  \
                ar[_i], br[_j], acc[(g) * 4 + _i][_j], 0, 0, 0);              \
    __builtin_amdgcn_s_setprio(0);                                            \
  } while (0)

#define ITER(ii, LASTF)                                                        \
  do {                                                                         \
    const int t0 = 2 * (ii), t1 = t0 + 1;                                      \
    /*P0*/ RD_A(aA, 0, sw0, 0); RD_B(bA, sw0, 0); STAGE(1, 1, t1);             \
    SBAR(); WAITL(); MM(0, aA, bA); SBAR2();                                   \
    /*P1*/ RD_A(aB, 1, sw0, 0); RD_A(aC, 0, sw1, 0); STAGE(1, 2, t1);          \
    SBAR(); WAITL(); MM(1, aB, bA); SBAR2();                                   \
    /*P2*/ RD_B(bB, sw1, 0); RD_A(aD, 1, sw1, 0); STAGE(1, 3, t1);             \
    SBAR(); WAITL(); MM(0, aC, bB); SBAR2();                                   \
    /*P3*/ if (!(LASTF)) { STAGE(0, 0, t0 + 2); WAITV(2); } else { WAITV(0); } \
    SBAR(); WAITL(); MM(1, aD, bB); SBAR2();                                   \
    /*P4*/ RD_A(aA, 0, sw0, 1); RD_B(bA, sw0, 1);                              \
    if (!(LASTF)) STAGE(0, 1, t0 + 2);                                         \
    SBAR(); WAITL(); MM(0, aA, bA); SBAR2();                                   \
    /*P5*/ RD_A(aB, 1, sw0, 1); RD_A(aC, 0, sw1, 1);                           \
    if (!(LASTF)) STAGE(0, 2, t0 + 2);                                         \
    SBAR(); WAITL(); MM(1, aB, bA); SBAR2();                                   \
    /*P6*/ RD_B(bB, sw1, 1); RD_A(aD, 1, sw1, 1);                              \
    if (!(LASTF)) STAGE(0, 3, t0 + 2);                                         \
    SBAR(); WAITL(); MM(0, aC, bB); SBAR2();                                   \
    /*P7*/ if (!(LASTF)) { STAGE(1, 0, t1 + 2); WAITV(2); }                    \
    SBAR(); WAITL(); MM(1, aD, bB); SBAR2();                                   \
  } while (0)

  STAGE(0, 0, 0); STAGE(0, 1, 0); STAGE(0, 2, 0); STAGE(0, 3, 0);
  STAGE(1, 0, 1);
  WAITV(2);
  SBAR2();

#pragma unroll 1
  for (int it = 0; it < 5; ++it) { ITER(it, 0); }
  ITER(5, 1);

#undef STAGE
#undef RD_A
#undef RD_B
#undef MM
#undef ITER

  // ---------------- epilogue ----------------
  if constexpr (OUTMODE == 1) {
    unsigned short* sm = (unsigned short*)smem;
    const int mat = bn / 3;  // 0..8 -> Q,K,V
    const float scale = (mat == 0) ? 0.125f : 1.0f;
    const float* bp = (mat == 0) ? bias0 : (mat == 1 ? bias1 : bias2);
    const int cb = c0 - mat * 768;
    float bv4[4];
#pragma unroll
    for (int n = 0; n < 4; ++n) bv4[n] = bp[cb + (wc << 6) + (n << 4) + lr];
#pragma unroll
    for (int m = 0; m < 8; ++m)
#pragma unroll
      for (int n = 0; n < 4; ++n)
#pragma unroll
        for (int r = 0; r < 4; ++r) {
          int row = (wr << 7) + (m << 4) + (lg << 2) + r;  // == c
          int col = (wc << 6) + (n << 4) + lr;
          sm[row * 256 + col] = f2bf((acc[m][n][r] + bv4[n]) * scale);
        }
    __syncthreads();
    // store to [c][h][i][d]: addr = ((c*12 + h)*128 + i)*64 + d
    unsigned short* outm = (unsigned short*)OutP + (size_t)mat * 25165824;
    const int hbase = cb >> 6;
    const int i_idx = r0 >> 8;  // fixed i for this tile
#pragma unroll
    for (int p = 0; p < 16; ++p) {
      int idx = p * 512 + tid;         // 8192 chunks of 16B
      int row = idx >> 5;              // c
      int hl = (idx >> 3) & 3;         // head-local (4 heads per 256-col tile)
      int d8 = idx & 7;
      *(u16x8*)(outm + ((((size_t)(row * HH + hbase + hl)) << 7 | i_idx) << 6) + d8 * 8) =
          *(const u16x8*)(sm + row * 256 + hl * 64 + d8 * 8);
    }
  } else {
    float* out = (float*)OutP;
    float bv4[4];
#pragma unroll
    for (int n = 0; n < 4; ++n) bv4[n] = bias0[c0 + (wc << 6) + (n << 4) + lr];
#pragma unroll
    for (int m = 0; m < 8; ++m)
#pragma unroll
      for (int n = 0; n < 4; ++n)
#pragma unroll
        for (int r = 0; r < 4; ++r) {
          int u = r0 + (wr << 7) + (m << 4) + (lg << 2) + r;  // c-major row
          int t = ((u & 127) << 8) | (u >> 7);                 // token
          int col = (wc << 6) + (n << 4) + lr;
          out[(size_t)t * EE + c0 + col] = acc[m][n][r] + bv4[n];
        }
  }
}

// ---------------- attention per (c,h) -----------------------------------------
// LDS 52.2 KB (V^T swizzled + P), 3 blocks/CU. K and Q read direct from global
// (L2/L3-hot, just produced by the QKV GEMM). probs stored from registers
// pre-PV (R3 structure). ctx bounced through each wave's private ps band.
__global__ __launch_bounds__(256, 3) void attn_kernel(
    const unsigned short* __restrict__ qatt, const unsigned short* __restrict__ katt,
    const unsigned short* __restrict__ vatt, const unsigned char* __restrict__ pmask,
    float* __restrict__ probs, unsigned short* __restrict__ ctx) {
  __shared__ unsigned short vt[64 * 136];   // V^T, j-block XOR-swizzled
  __shared__ unsigned short ps[128 * 136];  // P bf16; later per-wave ctx bands
  const int bx = blockIdx.x;
  const int c = bx / HH, h = bx - (bx / HH) * HH;
  const int tid = threadIdx.x;
  const int wid = tid >> 6, lane = tid & 63;
  const int lr = lane & 15, lg = lane >> 4;
  const int wr = wid;
  const size_t blk = ((size_t)(c * HH + h)) << 13;  // *128*64
  const unsigned short* qb = qatt + blk;
  const unsigned short* kb = katt + blk;
  const unsigned short* vb = vatt + blk;

  // Q fragments (issue-early)
  bf16x8 qf[2][2];
#pragma unroll
  for (int m = 0; m < 2; ++m)
#pragma unroll
    for (int kk = 0; kk < 2; ++kk) {
      int qi = (wr << 5) + (m << 4) + lr;
      qf[m][kk] = *(const bf16x8*)(qb + qi * 64 + kk * 32 + (lg << 3));
    }

  // stage V^T with j-block XOR swizzle: element (d, j) -> vt[d*136 + (j ^ ((d>>3)&7)<<3)]
#pragma unroll
  for (int p = 0; p < 4; ++p) {
    int chunk = p * 256 + tid;
    int j = chunk >> 3, d0 = (chunk & 7) << 3;
    bf16x8 vv = *(const bf16x8*)(vb + j * 64 + d0);
    int jx = j ^ (((d0 >> 3) & 7) << 3);  // (d0+u)>>3 == d0>>3 for u<8
#pragma unroll
    for (int u = 0; u < 8; ++u) vt[(d0 + u) * 136 + jx] = (unsigned short)vv[u];
  }

  // S = Q K^T, K fragments direct from global
  f32x4 s[2][8] = {};
#pragma unroll
  for (int kk = 0; kk < 2; ++kk) {
    bf16x8 kf[8];
#pragma unroll
    for (int n = 0; n < 8; ++n)
      kf[n] = *(const bf16x8*)(kb + (n * 16 + lr) * 64 + kk * 32 + (lg << 3));
#pragma unroll
    for (int m = 0; m < 2; ++m)
#pragma unroll
      for (int n = 0; n < 8; ++n)
        s[m][n] = __builtin_amdgcn_mfma_f32_16x16x32_bf16(qf[m][kk], kf[n],
                                                          s[m][n], 0, 0, 0);
  }

#pragma unroll
  for (int n = 0; n < 8; ++n) {
    if (pmask[(size_t)(n * 16 + lr) * CC + c] != 0) {
      f32x4 neg = {-10000.0f, -10000.0f, -10000.0f, -10000.0f};
      s[0][n] = neg;
      s[1][n] = neg;
    }
  }

  float inv_[2][4];
#pragma unroll
  for (int m = 0; m < 2; ++m) {
    f32x4 mx = s[m][0];
#pragma unroll
    for (int n = 1; n < 8; ++n)
#pragma unroll
      for (int r = 0; r < 4; ++r) mx[r] = fmaxf(mx[r], s[m][n][r]);
#pragma unroll
    for (int r = 0; r < 4; ++r) {
      float t = mx[r];
      t = fmaxf(t, __shfl_xor(t, 1));
      t = fmaxf(t, __shfl_xor(t, 2));
      t = fmaxf(t, __shfl_xor(t, 4));
      t = fmaxf(t, __shfl_xor(t, 8));
      mx[r] = t;
    }
    f32x4 sum = {};
#pragma unroll
    for (int n = 0; n < 8; ++n)
#pragma unroll
      for (int r = 0; r < 4; ++r) {
        float e = exp2f((s[m][n][r] - mx[r]) * 1.44269504f);
        s[m][n][r] = e;
        sum[r] += e;
      }
#pragma unroll
    for (int r = 0; r < 4; ++r) {
      float t = sum[r];
      t += __shfl_xor(t, 1);
      t += __shfl_xor(t, 2);
      t += __shfl_xor(t, 4);
      t += __shfl_xor(t, 8);
      inv_[m][r] = __builtin_amdgcn_rcpf(t);
    }
  }

  // probs (fp32, from registers) + P (bf16) to LDS
  const size_t pbase = ((size_t)h * CC + c) * (size_t)(128 * 128);
#pragma unroll
  for (int m = 0; m < 2; ++m)
#pragma unroll
    for (int n = 0; n < 8; ++n)
#pragma unroll
      for (int r = 0; r < 4; ++r) {
        float pv = s[m][n][r] * inv_[m][r];
        int i = (wr << 5) + (m << 4) + (lg << 2) + r;
        int j = (n << 4) + lr;
        probs[pbase + (size_t)i * 128 + j] = pv;
        ps[i * 136 + j] = f2bf(pv);
      }

  __syncthreads();  // vt + ps complete

  f32x4 o[2][4] = {};
#pragma unroll
  for (int kk = 0; kk < 4; ++kk) {
    bf16x8 pa[2], vbr[4];
#pragma unroll
    for (int m = 0; m < 2; ++m)
      pa[m] = *(const bf16x8*)&ps[((wr << 5) + (m << 4) + lr) * 136 + kk * 32 + (lg << 3)];
#pragma unroll
    for (int n = 0; n < 4; ++n) {
      int d = (n << 4) + lr;
      int jb = (kk * 32 + (lg << 3)) ^ ((((d >> 3) & 7)) << 3);
      vbr[n] = *(const bf16x8*)&vt[d * 136 + jb];
    }
#pragma unroll
    for (int m = 0; m < 2; ++m)
#pragma unroll
      for (int n = 0; n < 4; ++n)
        o[m][n] = __builtin_amdgcn_mfma_f32_16x16x32_bf16(pa[m], vbr[n], o[m][n], 0, 0, 0);
  }

  // ctx bounce into this wave's private ps band (rows wr*32..wr*32+31 only)
  unsigned short* band = ps + wr * 32 * 136;
#pragma unroll
  for (int m = 0; m < 2; ++m)
#pragma unroll
    for (int n = 0; n < 4; ++n)
#pragma unroll
      for (int r = 0; r < 4; ++r) {
        int il = (m << 4) + (lg << 2) + r;
        int d = (n << 4) + lr;
        band[il * 64 + d] = f2bf(o[m][n][r]);
      }
  __syncthreads();

  // vectorized ctx stores (c-major [c*128+i][768])
#pragma unroll
  for (int p = 0; p < 4; ++p) {
    int chunk = p * 256 + tid;
    int i = chunk >> 3, d8 = chunk & 7;
    *(u16x8*)(ctx + ((size_t)c * 128 + i) * EE + h * 64 + d8 * 8) =
        *(const u16x8*)(ps + (i >> 5) * (32 * 136) + (i & 31) * 64 + d8 * 8);
  }
}

extern "C" void kernel_launch(void* const* d_in, const int* in_sizes, int n_in,
                              void* d_out, int out_size, void* d_ws, size_t ws_size,
                              hipStream_t stream) {
  const float* x = (const float*)d_in[0];
  const unsigned char* pm = (const unsigned char*)d_in[1];
  const float* Wq = (const float*)d_in[2];
  const float* bq = (const float*)d_in[3];
  const float* Wk = (const float*)d_in[4];
  const float* bk = (const float*)d_in[5];
  const float* Wv = (const float*)d_in[6];
  const float* bv = (const float*)d_in[7];
  const float* Wo = (const float*)d_in[8];
  const float* bo = (const float*)d_in[9];

  unsigned short* ws = (unsigned short*)d_ws;
  unsigned short* xb = ws;                       // 25165824 (x_bf16, later ctx c-major)
  unsigned short* qkv = xb + 25165824;           // 3 x 25165824 ([c][h][i][d] per matrix)
  unsigned short* wcast = qkv + 75497472;        // 4 x 589824 (Wq|Wk|Wv|Wo)

  float* outp = (float*)d_out;
  float* probs = outp + 25165824;

  cast_all<<<13440, 256, 0, stream>>>(x, Wq, Wk, Wv, Wo, xb, wcast);
  gemm256<1><<<1152, 512, 0, stream>>>(xb, wcast, (void*)qkv, bq, bk, bv);
  attn_kernel<<<CC * HH, 256, 0, stream>>>(qkv, qkv + 25165824, qkv + 50331648,
                                           pm, probs, xb /*ctx c-major*/);
  gemm256<0><<<384, 512, 0, stream>>>(xb, wcast + 1769472, (void*)outp, bo,
                                      nullptr, nullptr);
}

// Round 6
// 326.589 us; speedup vs baseline: 1.0589x; 1.0589x over previous
//
#include <hip/hip_runtime.h>
#include <hip/hip_bf16.h>

typedef __attribute__((ext_vector_type(8))) short bf16x8;
typedef __attribute__((ext_vector_type(4))) float f32x4;
typedef __attribute__((ext_vector_type(8))) unsigned short u16x8;

#define RR 128
#define CC 256
#define EE 768
#define HH 12
#define DKK 64
#define NQKV 2304

__device__ __forceinline__ unsigned short f2bf(float f) {
  union { float f; unsigned u; } v; v.f = f;
  unsigned u = v.u;
  unsigned r = (u + 0x7fffu + ((u >> 16) & 1u)) >> 16;
  return (unsigned short)r;
}

__device__ __forceinline__ void gload16(const unsigned short* g, char* l) {
  __builtin_amdgcn_global_load_lds((const __attribute__((address_space(1))) void*)g,
                                   (__attribute__((address_space(3))) void*)l, 16, 0, 0);
}

// ---------------- fused cast fp32 -> bf16 (x + 4 weight matrices) -----------
__global__ void cast_all(const float* __restrict__ x, const float* __restrict__ w0,
                         const float* __restrict__ w1, const float* __restrict__ w2,
                         const float* __restrict__ w3, unsigned short* __restrict__ xb,
                         unsigned short* __restrict__ wdst) {
  int b = blockIdx.x;
  const float* src;
  unsigned short* dst;
  int t;
  if (b < 12288) {
    src = x; dst = xb; t = b * 256 + (int)threadIdx.x;
  } else {
    int bb = b - 12288;
    int m = bb / 288;
    src = (m == 0) ? w0 : (m == 1) ? w1 : (m == 2) ? w2 : w3;
    dst = wdst + (size_t)m * 589824;
    t = (bb - m * 288) * 256 + (int)threadIdx.x;
  }
  const float4* s = (const float4*)src + (size_t)t * 2;
  float4 a = s[0], bq = s[1];
  u16x8 o;
  o[0] = f2bf(a.x); o[1] = f2bf(a.y); o[2] = f2bf(a.z); o[3] = f2bf(a.w);
  o[4] = f2bf(bq.x); o[5] = f2bf(bq.y); o[6] = f2bf(bq.z); o[7] = f2bf(bq.w);
  *(u16x8*)(dst + (size_t)t * 8) = o;
}

// ---------------- 256x256 8-phase GEMM: C = A[M][768] * B[N][768]^T (+bias) --
// OUTMODE 1 (QKV): writes bf16 in attention-native layout [c][h][i][d] per
//   matrix (Q scaled by 0.125), via 128KB LDS epilogue.
// OUTMODE 0 (out-proj): A rows are c-major ctx (u = c*128+i); epilogue
//   un-permutes to token-major fp32 out[t*768+col], t = (u&127)<<8 | (u>>7).

#define SBAR() do { __builtin_amdgcn_sched_barrier(0); __builtin_amdgcn_s_barrier(); } while (0)
#define SBAR2() do { __builtin_amdgcn_sched_barrier(0); __builtin_amdgcn_s_barrier(); __builtin_amdgcn_sched_barrier(0); } while (0)
#define WAITL() do { asm volatile("s_waitcnt lgkmcnt(0)" ::: "memory"); __builtin_amdgcn_sched_barrier(0); } while (0)
#define WAITV(N) asm volatile("s_waitcnt vmcnt(" #N ")" ::: "memory")

template <int OUTMODE>
__global__ __launch_bounds__(512, 2) void gemm256(
    const unsigned short* __restrict__ A, const unsigned short* __restrict__ Bw,
    void* __restrict__ OutP, const float* __restrict__ bias0,
    const float* __restrict__ bias1, const float* __restrict__ bias2) {
  __shared__ __align__(16) char smem[131072];
  const int nwg = gridDim.x;
  const int chunk = nwg >> 3;
  const int swz = ((int)blockIdx.x & 7) * chunk + ((int)blockIdx.x >> 3);
  const int bm = swz % 128, bn = swz / 128;
  const int r0 = bm << 8, c0 = bn << 8;

  const int tid = threadIdx.x;
  const int w = tid >> 6, lane = tid & 63;
  const int wr = w >> 2, wc = w & 3;
  const int lr = lane & 15, lg = lane >> 4;
  const int l8 = lane >> 3, l7 = lane & 7;
  const int swzc = (l7 ^ (l8 & 7)) << 3;  // element offset, pre-swizzled source
  const unsigned short* pa = A + (size_t)(r0 + l8) * EE + swzc;
  const unsigned short* pb = Bw + (size_t)(c0 + l8) * EE + swzc;
  const int j0 = w, j1 = w + 8;

  // ds_read byte offsets
  const int aoff = (wr << 14) + (lr << 7);
  const int boff = 32768 + ((wc >> 1) << 14) + ((wc & 1) << 13) + (lr << 7);
  const int sw0 = ((0 + lg) ^ (lr & 7)) << 4;  // kk=0 col16 = lg
  const int sw1 = ((4 + lg) ^ (lr & 7)) << 4;  // kk=1 col16 = 4+lg

  f32x4 acc[8][4] = {};
  bf16x8 aA[4], aB[4], aC[4], aD[4], bA[4], bB[4];

#define STAGE(s, H, t)                                                        \
  do {                                                                        \
    const unsigned short* _src = ((H) < 2 ? pa : pb) +                        \
        (size_t)(((H) & 1) * 128) * EE + (size_t)(t) * 64;                    \
    char* _d = smem + (s) * 65536 + ((H) >= 2 ? 32768 : 0) + ((H) & 1) * 16384; \
    gload16(_src + (size_t)j0 * 8 * EE, _d + j0 * 1024);                      \
    gload16(_src + (size_t)j1 * 8 * EE, _d + j1 * 1024);                      \
  } while (0)

#define RD_A(dst, g, SW, s)                                                   \
  _Pragma("unroll") for (int _m = 0; _m < 4; ++_m)                            \
      dst[_m] = *(const bf16x8*)(smem + (s) * 65536 + aoff + (g) * 8192 +     \
                                 _m * 2048 + (SW));

#define RD_B(dst, SW, s)                                                      \
  _Pragma("unroll") for (int _n = 0; _n < 4; ++_n)                            \
      dst[_n] = *(const bf16x8*)(smem + (s) * 65536 + boff + _n * 2048 + (SW));

#define MM(g, ar, br)                                                         \
  do {                                                                        \
    __builtin_amdgcn_s_setprio(1);                                            \
    _Pragma("unroll") for (int _i = 0; _i < 4; ++_i)                          \
        _Pragma("unroll") for (int _j = 0; _j < 4; ++_j)                      \
            acc[(g) * 4 + _i][_j] = __builtin_amdgcn_mfma_f32_16x16x32_bf16(  \
                ar[_i], br[_j], acc[(g) * 4 + _i][_j], 0, 0, 0);              \
    __builtin_amdgcn_s_setprio(0);                                            \
  } while (0)

#define ITER(ii, LASTF)                                                        \
  do {                                                                         \
    const int t0 = 2 * (ii), t1 = t0 + 1;                                      \
    /*P0*/ RD_A(aA, 0, sw0, 0); RD_B(bA, sw0, 0); STAGE(1, 1, t1);             \
    SBAR(); WAITL(); MM(0, aA, bA); SBAR2();                                   \
    /*P1*/ RD_A(aB, 1, sw0, 0); RD_A(aC, 0, sw1, 0); STAGE(1, 2, t1);          \
    SBAR(); WAITL(); MM(1, aB, bA); SBAR2();                                   \
    /*P2*/ RD_B(bB, sw1, 0); RD_A(aD, 1, sw1, 0); STAGE(1, 3, t1);             \
    SBAR(); WAITL(); MM(0, aC, bB); SBAR2();                                   \
    /*P3*/ if (!(LASTF)) { STAGE(0, 0, t0 + 2); WAITV(2); } else { WAITV(0); } \
    SBAR(); WAITL(); MM(1, aD, bB); SBAR2();                                   \
    /*P4*/ RD_A(aA, 0, sw0, 1); RD_B(bA, sw0, 1);                              \
    if (!(LASTF)) STAGE(0, 1, t0 + 2);                                         \
    SBAR(); WAITL(); MM(0, aA, bA); SBAR2();                                   \
    /*P5*/ RD_A(aB, 1, sw0, 1); RD_A(aC, 0, sw1, 1);                           \
    if (!(LASTF)) STAGE(0, 2, t0 + 2);                                         \
    SBAR(); WAITL(); MM(1, aB, bA); SBAR2();                                   \
    /*P6*/ RD_B(bB, sw1, 1); RD_A(aD, 1, sw1, 1);                              \
    if (!(LASTF)) STAGE(0, 3, t0 + 2);                                         \
    SBAR(); WAITL(); MM(0, aC, bB); SBAR2();                                   \
    /*P7*/ if (!(LASTF)) { STAGE(1, 0, t1 + 2); WAITV(2); }                    \
    SBAR(); WAITL(); MM(1, aD, bB); SBAR2();                                   \
  } while (0)

  STAGE(0, 0, 0); STAGE(0, 1, 0); STAGE(0, 2, 0); STAGE(0, 3, 0);
  STAGE(1, 0, 1);
  WAITV(2);
  SBAR2();

#pragma unroll 1
  for (int it = 0; it < 5; ++it) { ITER(it, 0); }
  ITER(5, 1);

#undef STAGE
#undef RD_A
#undef RD_B
#undef MM
#undef ITER

  // ---------------- epilogue ----------------
  if constexpr (OUTMODE == 1) {
    unsigned short* sm = (unsigned short*)smem;
    const int mat = bn / 3;  // 0..8 -> Q,K,V
    const float scale = (mat == 0) ? 0.125f : 1.0f;
    const float* bp = (mat == 0) ? bias0 : (mat == 1 ? bias1 : bias2);
    const int cb = c0 - mat * 768;
    float bv4[4];
#pragma unroll
    for (int n = 0; n < 4; ++n) bv4[n] = bp[cb + (wc << 6) + (n << 4) + lr];
#pragma unroll
    for (int m = 0; m < 8; ++m)
#pragma unroll
      for (int n = 0; n < 4; ++n)
#pragma unroll
        for (int r = 0; r < 4; ++r) {
          int row = (wr << 7) + (m << 4) + (lg << 2) + r;  // == c
          int col = (wc << 6) + (n << 4) + lr;
          sm[row * 256 + col] = f2bf((acc[m][n][r] + bv4[n]) * scale);
        }
    __syncthreads();
    // store to [c][h][i][d]: addr = ((c*12 + h)*128 + i)*64 + d
    unsigned short* outm = (unsigned short*)OutP + (size_t)mat * 25165824;
    const int hbase = cb >> 6;
    const int i_idx = r0 >> 8;  // fixed i for this tile
#pragma unroll
    for (int p = 0; p < 16; ++p) {
      int idx = p * 512 + tid;         // 8192 chunks of 16B
      int row = idx >> 5;              // c
      int hl = (idx >> 3) & 3;         // head-local (4 heads per 256-col tile)
      int d8 = idx & 7;
      *(u16x8*)(outm + ((((size_t)(row * HH + hbase + hl)) << 7 | i_idx) << 6) + d8 * 8) =
          *(const u16x8*)(sm + row * 256 + hl * 64 + d8 * 8);
    }
  } else {
    float* out = (float*)OutP;
    float bv4[4];
#pragma unroll
    for (int n = 0; n < 4; ++n) bv4[n] = bias0[c0 + (wc << 6) + (n << 4) + lr];
#pragma unroll
    for (int m = 0; m < 8; ++m)
#pragma unroll
      for (int n = 0; n < 4; ++n)
#pragma unroll
        for (int r = 0; r < 4; ++r) {
          int u = r0 + (wr << 7) + (m << 4) + (lg << 2) + r;  // c-major row
          int t = ((u & 127) << 8) | (u >> 7);                 // token
          int col = (wc << 6) + (n << 4) + lr;
          out[(size_t)t * EE + c0 + col] = acc[m][n][r] + bv4[n];
        }
  }
}

// ---------------- attention: one block per column c, head-looped -------------
// 512 threads = 8 waves; wave w owns Q-rows [w*16, w*16+16). Double-buffered
// K (row-major pad 72) + V^T (pad 136) in LDS; next head's K/V/Q prefetched
// into registers at head start, written to the idle buffer post-PV.
// One __syncthreads per head. P and ctx bands are wave-private.
__global__ __launch_bounds__(512, 2) void attn_col(
    const unsigned short* __restrict__ qatt, const unsigned short* __restrict__ katt,
    const unsigned short* __restrict__ vatt, const unsigned char* __restrict__ pmask,
    float* __restrict__ probs, unsigned short* __restrict__ ctx) {
  // shorts layout: ks[2] @ 0/9216 (9216 each), vt[2] @ 18432/+8704, ps @ 35840
  __shared__ unsigned short sm[53248];  // 104 KB
  const int c = blockIdx.x;
  const int tid = threadIdx.x;
  const int w = tid >> 6, lane = tid & 63;
  const int lr = lane & 15, lg = lane >> 4;
  // staging decomposition: 2 chunks of 16B per thread per matrix
  const int j0 = tid >> 3;          // rows 0..63
  const int j1 = 64 + j0;           // rows 64..127
  const int d00 = (tid & 7) << 3;   // d offset 0..56
  const int kst0 = j0 * 72 + d00, kst1 = j1 * 72 + d00;
  unsigned short* ps = sm + 35840;
  const size_t cb12 = (size_t)c * HH;

  // pmask per j (head-invariant)
  unsigned char pmv[8];
#pragma unroll
  for (int n = 0; n < 8; ++n) pmv[n] = pmask[(size_t)((n << 4) + lr) * CC + c];

  // prologue: stage head 0
  {
    const unsigned short* kb = katt + (cb12 << 13);
    const unsigned short* vb = vatt + (cb12 << 13);
    bf16x8 k0 = *(const bf16x8*)(kb + j0 * 64 + d00);
    bf16x8 k1 = *(const bf16x8*)(kb + j1 * 64 + d00);
    bf16x8 v0 = *(const bf16x8*)(vb + j0 * 64 + d00);
    bf16x8 v1 = *(const bf16x8*)(vb + j1 * 64 + d00);
    *(bf16x8*)(sm + kst0) = k0;
    *(bf16x8*)(sm + kst1) = k1;
    unsigned short* vt0 = sm + 18432;
#pragma unroll
    for (int u = 0; u < 8; ++u) vt0[(d00 + u) * 136 + j0] = (unsigned short)v0[u];
#pragma unroll
    for (int u = 0; u < 8; ++u) vt0[(d00 + u) * 136 + j1] = (unsigned short)v1[u];
  }
  bf16x8 qf0, qf1;
  {
    const unsigned short* qb = qatt + (cb12 << 13);
    qf0 = *(const bf16x8*)(qb + ((w << 4) + lr) * 64 + (lg << 3));
    qf1 = *(const bf16x8*)(qb + ((w << 4) + lr) * 64 + 32 + (lg << 3));
  }
  __syncthreads();

  int cur = 0;
#pragma unroll 1
  for (int h = 0; h < HH; ++h) {
    const unsigned short* ksc = sm + cur * 9216;
    const unsigned short* vtc = sm + 18432 + cur * 8704;

    // prefetch next head into registers (lands under this head's compute)
    bf16x8 kr0{}, kr1{}, vr0{}, vr1{}, qn0{}, qn1{};
    const bool pf = (h + 1 < HH);
    if (pf) {
      const unsigned short* kb = katt + ((cb12 + h + 1) << 13);
      const unsigned short* vb = vatt + ((cb12 + h + 1) << 13);
      const unsigned short* qb = qatt + ((cb12 + h + 1) << 13);
      kr0 = *(const bf16x8*)(kb + j0 * 64 + d00);
      kr1 = *(const bf16x8*)(kb + j1 * 64 + d00);
      vr0 = *(const bf16x8*)(vb + j0 * 64 + d00);
      vr1 = *(const bf16x8*)(vb + j1 * 64 + d00);
      qn0 = *(const bf16x8*)(qb + ((w << 4) + lr) * 64 + (lg << 3));
      qn1 = *(const bf16x8*)(qb + ((w << 4) + lr) * 64 + 32 + (lg << 3));
    }

    // S = Q K^T (wave: 16 rows x 128 cols)
    f32x4 s[8] = {};
#pragma unroll
    for (int kk = 0; kk < 2; ++kk) {
      bf16x8 kf[8];
#pragma unroll
      for (int n = 0; n < 8; ++n)
        kf[n] = *(const bf16x8*)&ksc[((n << 4) + lr) * 72 + kk * 32 + (lg << 3)];
      bf16x8 q = kk ? qf1 : qf0;
#pragma unroll
      for (int n = 0; n < 8; ++n)
        s[n] = __builtin_amdgcn_mfma_f32_16x16x32_bf16(q, kf[n], s[n], 0, 0, 0);
    }

#pragma unroll
    for (int n = 0; n < 8; ++n) {
      if (pmv[n]) {
        f32x4 neg = {-10000.0f, -10000.0f, -10000.0f, -10000.0f};
        s[n] = neg;
      }
    }

    // softmax over j
    f32x4 mxv = s[0];
#pragma unroll
    for (int n = 1; n < 8; ++n)
#pragma unroll
      for (int r = 0; r < 4; ++r) mxv[r] = fmaxf(mxv[r], s[n][r]);
#pragma unroll
    for (int r = 0; r < 4; ++r) {
      float t = mxv[r];
      t = fmaxf(t, __shfl_xor(t, 1));
      t = fmaxf(t, __shfl_xor(t, 2));
      t = fmaxf(t, __shfl_xor(t, 4));
      t = fmaxf(t, __shfl_xor(t, 8));
      mxv[r] = t;
    }
    f32x4 sum = {};
#pragma unroll
    for (int n = 0; n < 8; ++n)
#pragma unroll
      for (int r = 0; r < 4; ++r) {
        float e = exp2f((s[n][r] - mxv[r]) * 1.44269504f);
        s[n][r] = e;
        sum[r] += e;
      }
    float inv_[4];
#pragma unroll
    for (int r = 0; r < 4; ++r) {
      float t = sum[r];
      t += __shfl_xor(t, 1);
      t += __shfl_xor(t, 2);
      t += __shfl_xor(t, 4);
      t += __shfl_xor(t, 8);
      inv_[r] = __builtin_amdgcn_rcpf(t);
    }

    // probs (fp32, from registers) + P (bf16) to wave-private band
    const size_t pbase = ((size_t)h * CC + c) << 14;
#pragma unroll
    for (int n = 0; n < 8; ++n)
#pragma unroll
      for (int r = 0; r < 4; ++r) {
        float pv = s[n][r] * inv_[r];
        int i = (w << 4) + (lg << 2) + r;
        int j = (n << 4) + lr;
        probs[pbase + (size_t)i * 128 + j] = pv;
        ps[i * 136 + j] = f2bf(pv);
      }

    // PV (no barrier: P band and V^T[cur] are already consistent)
    f32x4 o[4] = {};
#pragma unroll
    for (int kk = 0; kk < 4; ++kk) {
      bf16x8 pa = *(const bf16x8*)&ps[((w << 4) + lr) * 136 + kk * 32 + (lg << 3)];
      bf16x8 vbr[4];
#pragma unroll
      for (int n = 0; n < 4; ++n)
        vbr[n] = *(const bf16x8*)&vtc[((n << 4) + lr) * 136 + kk * 32 + (lg << 3)];
#pragma unroll
      for (int n = 0; n < 4; ++n)
        o[n] = __builtin_amdgcn_mfma_f32_16x16x32_bf16(pa, vbr[n], o[n], 0, 0, 0);
    }

    // write prefetched next head into the idle buffers
    if (pf) {
      unsigned short* ksn = sm + (cur ^ 1) * 9216;
      unsigned short* vtn = sm + 18432 + (cur ^ 1) * 8704;
      *(bf16x8*)(ksn + kst0) = kr0;
      *(bf16x8*)(ksn + kst1) = kr1;
#pragma unroll
      for (int u = 0; u < 8; ++u) vtn[(d00 + u) * 136 + j0] = (unsigned short)vr0[u];
#pragma unroll
      for (int u = 0; u < 8; ++u) vtn[(d00 + u) * 136 + j1] = (unsigned short)vr1[u];
      qf0 = qn0; qf1 = qn1;
    }

    // ctx via wave-private bounce (reuse own P band, dead after PV)
    unsigned short* bandc = ps + ((w << 4) * 136);
#pragma unroll
    for (int n = 0; n < 4; ++n)
#pragma unroll
      for (int r = 0; r < 4; ++r)
        bandc[((lg << 2) + r) * 64 + (n << 4) + lr] = f2bf(o[n][r]);
#pragma unroll
    for (int q = 0; q < 2; ++q) {
      int fl = q * 64 + lane;
      int iL = fl >> 3, d8 = fl & 7;
      *(u16x8*)(ctx + ((size_t)c * 128 + (w << 4) + iL) * EE + h * 64 + d8 * 8) =
          *(const u16x8*)(bandc + iL * 64 + d8 * 8);
    }

    __syncthreads();
    cur ^= 1;
  }
}

extern "C" void kernel_launch(void* const* d_in, const int* in_sizes, int n_in,
                              void* d_out, int out_size, void* d_ws, size_t ws_size,
                              hipStream_t stream) {
  const float* x = (const float*)d_in[0];
  const unsigned char* pm = (const unsigned char*)d_in[1];
  const float* Wq = (const float*)d_in[2];
  const float* bq = (const float*)d_in[3];
  const float* Wk = (const float*)d_in[4];
  const float* bk = (const float*)d_in[5];
  const float* Wv = (const float*)d_in[6];
  const float* bv = (const float*)d_in[7];
  const float* Wo = (const float*)d_in[8];
  const float* bo = (const float*)d_in[9];

  unsigned short* ws = (unsigned short*)d_ws;
  unsigned short* xb = ws;                       // 25165824 (x_bf16, later ctx c-major)
  unsigned short* qkv = xb + 25165824;           // 3 x 25165824 ([c][h][i][d] per matrix)
  unsigned short* wcast = qkv + 75497472;        // 4 x 589824 (Wq|Wk|Wv|Wo)

  float* outp = (float*)d_out;
  float* probs = outp + 25165824;

  cast_all<<<13440, 256, 0, stream>>>(x, Wq, Wk, Wv, Wo, xb, wcast);
  gemm256<1><<<1152, 512, 0, stream>>>(xb, wcast, (void*)qkv, bq, bk, bv);
  attn_col<<<CC, 512, 0, stream>>>(qkv, qkv + 25165824, qkv + 50331648,
                                   pm, probs, xb /*ctx c-major*/);
  gemm256<0><<<384, 512, 0, stream>>>(xb, wcast + 1769472, (void*)outp, bo,
                                      nullptr, nullptr);
}

// Round 8
// 322.883 us; speedup vs baseline: 1.0711x; 1.0115x over previous
//
#include <hip/hip_runtime.h>
#include <hip/hip_bf16.h>

typedef __attribute__((ext_vector_type(8))) short bf16x8;
typedef __attribute__((ext_vector_type(4))) float f32x4;
typedef __attribute__((ext_vector_type(8))) unsigned short u16x8;

#define RR 128
#define CC 256
#define EE 768
#define HH 12
#define DKK 64
#define NQKV 2304

__device__ __forceinline__ unsigned short f2bf(float f) {
  union { float f; unsigned u; } v; v.f = f;
  unsigned u = v.u;
  unsigned r = (u + 0x7fffu + ((u >> 16) & 1u)) >> 16;
  return (unsigned short)r;
}

__device__ __forceinline__ void gload16(const unsigned short* g, char* l) {
  __builtin_amdgcn_global_load_lds((const __attribute__((address_space(1))) void*)g,
                                   (__attribute__((address_space(3))) void*)l, 16, 0, 0);
}

// ---------------- fused cast fp32 -> bf16 (x + 4 weight matrices) -----------
__global__ void cast_all(const float* __restrict__ x, const float* __restrict__ w0,
                         const float* __restrict__ w1, const float* __restrict__ w2,
                         const float* __restrict__ w3, unsigned short* __restrict__ xb,
                         unsigned short* __restrict__ wdst) {
  int b = blockIdx.x;
  const float* src;
  unsigned short* dst;
  int t;
  if (b < 12288) {
    src = x; dst = xb; t = b * 256 + (int)threadIdx.x;
  } else {
    int bb = b - 12288;
    int m = bb / 288;
    src = (m == 0) ? w0 : (m == 1) ? w1 : (m == 2) ? w2 : w3;
    dst = wdst + (size_t)m * 589824;
    t = (bb - m * 288) * 256 + (int)threadIdx.x;
  }
  const float4* s = (const float4*)src + (size_t)t * 2;
  float4 a = s[0], bq = s[1];
  u16x8 o;
  o[0] = f2bf(a.x); o[1] = f2bf(a.y); o[2] = f2bf(a.z); o[3] = f2bf(a.w);
  o[4] = f2bf(bq.x); o[5] = f2bf(bq.y); o[6] = f2bf(bq.z); o[7] = f2bf(bq.w);
  *(u16x8*)(dst + (size_t)t * 8) = o;
}

// ---------------- 256x256 8-phase GEMM: C = A[M][768] * B[N][768]^T (+bias) --
// OUTMODE 1 (QKV): writes bf16 in attention-native layout [c][h][i][d] per
//   matrix (Q scaled by 0.125), via 128KB LDS epilogue.
// OUTMODE 0 (out-proj): A rows are c-major ctx (u = c*128+i); epilogue
//   un-permutes to token-major fp32 out[t*768+col], t = (u&127)<<8 | (u>>7).

#define SBAR() do { __builtin_amdgcn_sched_barrier(0); __builtin_amdgcn_s_barrier(); } while (0)
#define SBAR2() do { __builtin_amdgcn_sched_barrier(0); __builtin_amdgcn_s_barrier(); __builtin_amdgcn_sched_barrier(0); } while (0)
#define WAITL() do { asm volatile("s_waitcnt lgkmcnt(0)" ::: "memory"); __builtin_amdgcn_sched_barrier(0); } while (0)
#define WAITV(N) asm volatile("s_waitcnt vmcnt(" #N ")" ::: "memory")

template <int OUTMODE>
__global__ __launch_bounds__(512, 2) void gemm256(
    const unsigned short* __restrict__ A, const unsigned short* __restrict__ Bw,
    void* __restrict__ OutP, const float* __restrict__ bias0,
    const float* __restrict__ bias1, const float* __restrict__ bias2) {
  __shared__ __align__(16) char smem[131072];
  const int nwg = gridDim.x;
  const int chunk = nwg >> 3;
  const int swz = ((int)blockIdx.x & 7) * chunk + ((int)blockIdx.x >> 3);
  const int bm = swz % 128, bn = swz / 128;
  const int r0 = bm << 8, c0 = bn << 8;

  const int tid = threadIdx.x;
  const int w = tid >> 6, lane = tid & 63;
  const int wr = w >> 2, wc = w & 3;
  const int lr = lane & 15, lg = lane >> 4;
  const int l8 = lane >> 3, l7 = lane & 7;
  const int swzc = (l7 ^ (l8 & 7)) << 3;  // element offset, pre-swizzled source
  const unsigned short* pa = A + (size_t)(r0 + l8) * EE + swzc;
  const unsigned short* pb = Bw + (size_t)(c0 + l8) * EE + swzc;
  const int j0 = w, j1 = w + 8;

  // ds_read byte offsets
  const int aoff = (wr << 14) + (lr << 7);
  const int boff = 32768 + ((wc >> 1) << 14) + ((wc & 1) << 13) + (lr << 7);
  const int sw0 = ((0 + lg) ^ (lr & 7)) << 4;  // kk=0 col16 = lg
  const int sw1 = ((4 + lg) ^ (lr & 7)) << 4;  // kk=1 col16 = 4+lg

  f32x4 acc[8][4] = {};
  bf16x8 aA[4], aB[4], aC[4], aD[4], bA[4], bB[4];

#define STAGE(s, H, t)                                                        \
  do {                                                                        \
    const unsigned short* _src = ((H) < 2 ? pa : pb) +                        \
        (size_t)(((H) & 1) * 128) * EE + (size_t)(t) * 64;                    \
    char* _d = smem + (s) * 65536 + ((H) >= 2 ? 32768 : 0) + ((H) & 1) * 16384; \
    gload16(_src + (size_t)j0 * 8 * EE, _d + j0 * 1024);                      \
    gload16(_src + (size_t)j1 * 8 * EE, _d + j1 * 1024);                      \
  } while (0)

#define RD_A(dst, g, SW, s)                                                   \
  _Pragma("unroll") for (int _m = 0; _m < 4; ++_m)                            \
      dst[_m] = *(const bf16x8*)(smem + (s) * 65536 + aoff + (g) * 8192 +     \
                                 _m * 2048 + (SW));

#define RD_B(dst, SW, s)                                                      \
  _Pragma("unroll") for (int _n = 0; _n < 4; ++_n)                            \
      dst[_n] = *(const bf16x8*)(smem + (s) * 65536 + boff + _n * 2048 + (SW));

#define MM(g, ar, br)                                                         \
  do {                                                                        \
    __builtin_amdgcn_s_setprio(1);                                            \
    _Pragma("unroll") for (int _i = 0; _i < 4; ++_i)                          \
        _Pragma("unroll") for (int _j = 0; _j < 4; ++_j)                      \
            acc[(g) * 4 + _i][_j] = __builtin_amdgcn_mfma_f32_16x16x32_bf16(  \
                ar[_i], br[_j], acc[(g) * 4 + _i][_j], 0, 0, 0);              \
    __builtin_amdgcn_s_setprio(0);                                            \
  } while (0)

#define ITER(ii, LASTF)                                                        \
  do {                                                                         \
    const int t0 = 2 * (ii), t1 = t0 + 1;                                      \
    /*P0*/ RD_A(aA, 0, sw0, 0); RD_B(bA, sw0, 0); STAGE(1, 1, t1);             \
    SBAR(); WAITL(); MM(0, aA, bA); SBAR2();                                   \
    /*P1*/ RD_A(aB, 1, sw0, 0); RD_A(aC, 0, sw1, 0); STAGE(1, 2, t1);          \
    SBAR(); WAITL(); MM(1, aB, bA); SBAR2();                                   \
    /*P2*/ RD_B(bB, sw1, 0); RD_A(aD, 1, sw1, 0); STAGE(1, 3, t1);             \
    SBAR(); WAITL(); MM(0, aC, bB); SBAR2();                                   \
    /*P3*/ if (!(LASTF)) { STAGE(0, 0, t0 + 2); WAITV(2); } else { WAITV(0); } \
    SBAR(); WAITL(); MM(1, aD, bB); SBAR2();                                   \
    /*P4*/ RD_A(aA, 0, sw0, 1); RD_B(bA, sw0, 1);                              \
    if (!(LASTF)) STAGE(0, 1, t0 + 2);                                         \
    SBAR(); WAITL(); MM(0, aA, bA); SBAR2();                                   \
    /*P5*/ RD_A(aB, 1, sw0, 1); RD_A(aC, 0, sw1, 1);                           \
    if (!(LASTF)) STAGE(0, 2, t0 + 2);                                         \
    SBAR(); WAITL(); MM(1, aB, bA); SBAR2();                                   \
    /*P6*/ RD_B(bB, sw1, 1); RD_A(aD, 1, sw1, 1);                              \
    if (!(LASTF)) STAGE(0, 3, t0 + 2);                                         \
    SBAR(); WAITL(); MM(0, aC, bB); SBAR2();                                   \
    /*P7*/ if (!(LASTF)) { STAGE(1, 0, t1 + 2); WAITV(2); }                    \
    SBAR(); WAITL(); MM(1, aD, bB); SBAR2();                                   \
  } while (0)

  STAGE(0, 0, 0); STAGE(0, 1, 0); STAGE(0, 2, 0); STAGE(0, 3, 0);
  STAGE(1, 0, 1);
  WAITV(2);
  SBAR2();

#pragma unroll 1
  for (int it = 0; it < 5; ++it) { ITER(it, 0); }
  ITER(5, 1);

#undef STAGE
#undef RD_A
#undef RD_B
#undef MM
#undef ITER

  // ---------------- epilogue ----------------
  if constexpr (OUTMODE == 1) {
    unsigned short* sm = (unsigned short*)smem;
    const int mat = bn / 3;  // 0..8 -> Q,K,V
    const float scale = (mat == 0) ? 0.125f : 1.0f;
    const float* bp = (mat == 0) ? bias0 : (mat == 1 ? bias1 : bias2);
    const int cb = c0 - mat * 768;
    float bv4[4];
#pragma unroll
    for (int n = 0; n < 4; ++n) bv4[n] = bp[cb + (wc << 6) + (n << 4) + lr];
#pragma unroll
    for (int m = 0; m < 8; ++m)
#pragma unroll
      for (int n = 0; n < 4; ++n)
#pragma unroll
        for (int r = 0; r < 4; ++r) {
          int row = (wr << 7) + (m << 4) + (lg << 2) + r;  // == c
          int col = (wc << 6) + (n << 4) + lr;
          sm[row * 256 + col] = f2bf((acc[m][n][r] + bv4[n]) * scale);
        }
    __syncthreads();
    // store to [c][h][i][d]: addr = ((c*12 + h)*128 + i)*64 + d
    unsigned short* outm = (unsigned short*)OutP + (size_t)mat * 25165824;
    const int hbase = cb >> 6;
    const int i_idx = r0 >> 8;  // fixed i for this tile
#pragma unroll
    for (int p = 0; p < 16; ++p) {
      int idx = p * 512 + tid;         // 8192 chunks of 16B
      int row = idx >> 5;              // c
      int hl = (idx >> 3) & 3;         // head-local (4 heads per 256-col tile)
      int d8 = idx & 7;
      *(u16x8*)(outm + ((((size_t)(row * HH + hbase + hl)) << 7 | i_idx) << 6) + d8 * 8) =
          *(const u16x8*)(sm + row * 256 + hl * 64 + d8 * 8);
    }
  } else {
    float* out = (float*)OutP;
    float bv4[4];
#pragma unroll
    for (int n = 0; n < 4; ++n) bv4[n] = bias0[c0 + (wc << 6) + (n << 4) + lr];
#pragma unroll
    for (int m = 0; m < 8; ++m)
#pragma unroll
      for (int n = 0; n < 4; ++n)
#pragma unroll
        for (int r = 0; r < 4; ++r) {
          int u = r0 + (wr << 7) + (m << 4) + (lg << 2) + r;  // c-major row
          int t = ((u & 127) << 8) | (u >> 7);                 // token
          int col = (wc << 6) + (n << 4) + lr;
          out[(size_t)t * EE + c0 + col] = acc[m][n][r] + bv4[n];
        }
  }
}

// ---------------- attention: one block per column c, head-looped -------------
// 512 threads = 8 waves; wave w owns Q-rows [w*16, w*16+16).
// K: unpadded [128][64] double-buffered, staged via global_load_lds with
//    pre-swizzled per-lane SOURCE (slot' = slot ^ (row&7)); reads XOR the same.
// V^T: [64][136] double-buffered, j-block XOR swizzle (R5-verified) kills the
//    16-way scatter-write conflict. Next head's V/Q prefetched into registers.
// One __syncthreads per head. P and ctx bands are wave-private.
__global__ __launch_bounds__(512, 2) void attn_col(
    const unsigned short* __restrict__ qatt, const unsigned short* __restrict__ katt,
    const unsigned short* __restrict__ vatt, const unsigned char* __restrict__ pmask,
    float* __restrict__ probs, unsigned short* __restrict__ ctx) {
  // shorts: ks[2] @ 0 / 8192 (8192 each); vt[2] @ 16384 / 25088 (8704 each);
  // ps @ 33792 (17408). total 51200 shorts = 100 KB.
  __shared__ unsigned short sm[51200];
  const int c = blockIdx.x;
  const int tid = threadIdx.x;
  const int w = tid >> 6, lane = tid & 63;
  const int lr = lane & 15, lg = lane >> 4;
  const int j0 = tid >> 3;          // rows 0..63 (chunk0); chunk1 = +64
  const int d00 = (tid & 7) << 3;   // d offset for V staging
  const int kslot = (((tid & 7) ^ ((tid >> 3) & 7)) << 3);  // K source swizzle
  const int dblk = (d00 >> 3) & 7;  // V j-block swizzle key
  unsigned short* ps = sm + 33792;
  const size_t cb12 = (size_t)c * HH;

  // pmask per j (head-invariant)
  unsigned char pmv[8];
#pragma unroll
  for (int n = 0; n < 8; ++n) pmv[n] = pmask[(size_t)((n << 4) + lr) * CC + c];

  // prologue: stage head 0 (K via gload16, V via swizzled scatter)
  {
    const unsigned short* kb = katt + (cb12 << 13);
    gload16(kb + j0 * 64 + kslot, (char*)sm + tid * 16);
    gload16(kb + (64 + j0) * 64 + kslot, (char*)sm + 8192 + tid * 16);
    const unsigned short* vb = vatt + (cb12 << 13);
    bf16x8 v0 = *(const bf16x8*)(vb + j0 * 64 + d00);
    bf16x8 v1 = *(const bf16x8*)(vb + (64 + j0) * 64 + d00);
    unsigned short* vt0 = sm + 16384;
    int jx0 = j0 ^ (dblk << 3);
    int jx1 = (64 + j0) ^ (dblk << 3);
#pragma unroll
    for (int u = 0; u < 8; ++u) vt0[(d00 + u) * 136 + jx0] = (unsigned short)v0[u];
#pragma unroll
    for (int u = 0; u < 8; ++u) vt0[(d00 + u) * 136 + jx1] = (unsigned short)v1[u];
  }
  bf16x8 qf0, qf1;
  {
    const unsigned short* qb = qatt + (cb12 << 13);
    qf0 = *(const bf16x8*)(qb + ((w << 4) + lr) * 64 + (lg << 3));
    qf1 = *(const bf16x8*)(qb + ((w << 4) + lr) * 64 + 32 + (lg << 3));
  }
  __syncthreads();

  int cur = 0;
#pragma unroll 1
  for (int h = 0; h < HH; ++h) {
    const unsigned short* ksc = sm + cur * 8192;
    const unsigned short* vtc = sm + 16384 + cur * 8704;
    const bool pf = (h + 1 < HH);

    // next head: K straight to idle LDS buffer (async), V/Q into registers
    bf16x8 vr0{}, vr1{}, qn0{}, qn1{};
    if (pf) {
      const unsigned short* kb = katt + ((cb12 + h + 1) << 13);
      char* ksn = (char*)sm + (cur ^ 1) * 16384;
      gload16(kb + j0 * 64 + kslot, ksn + tid * 16);
      gload16(kb + (64 + j0) * 64 + kslot, ksn + 8192 + tid * 16);
      const unsigned short* vb = vatt + ((cb12 + h + 1) << 13);
      const unsigned short* qb = qatt + ((cb12 + h + 1) << 13);
      vr0 = *(const bf16x8*)(vb + j0 * 64 + d00);
      vr1 = *(const bf16x8*)(vb + (64 + j0) * 64 + d00);
      qn0 = *(const bf16x8*)(qb + ((w << 4) + lr) * 64 + (lg << 3));
      qn1 = *(const bf16x8*)(qb + ((w << 4) + lr) * 64 + 32 + (lg << 3));
    }

    // S = Q K^T (wave: 16 rows x 128 cols); per-n kf loads keep regs low
    f32x4 s[8] = {};
#pragma unroll
    for (int n = 0; n < 8; ++n) {
      const unsigned short* krow = ksc + ((n << 4) + lr) * 64;
      bf16x8 k0 = *(const bf16x8*)(krow + ((lg ^ (lr & 7)) << 3));
      bf16x8 k1 = *(const bf16x8*)(krow + (((4 + lg) ^ (lr & 7)) << 3));
      s[n] = __builtin_amdgcn_mfma_f32_16x16x32_bf16(qf0, k0, s[n], 0, 0, 0);
      s[n] = __builtin_amdgcn_mfma_f32_16x16x32_bf16(qf1, k1, s[n], 0, 0, 0);
    }

#pragma unroll
    for (int n = 0; n < 8; ++n) {
      if (pmv[n]) {
        f32x4 neg = {-10000.0f, -10000.0f, -10000.0f, -10000.0f};
        s[n] = neg;
      }
    }

    // softmax over j
    f32x4 mxv = s[0];
#pragma unroll
    for (int n = 1; n < 8; ++n)
#pragma unroll
      for (int r = 0; r < 4; ++r) mxv[r] = fmaxf(mxv[r], s[n][r]);
#pragma unroll
    for (int r = 0; r < 4; ++r) {
      float t = mxv[r];
      t = fmaxf(t, __shfl_xor(t, 1));
      t = fmaxf(t, __shfl_xor(t, 2));
      t = fmaxf(t, __shfl_xor(t, 4));
      t = fmaxf(t, __shfl_xor(t, 8));
      mxv[r] = t;
    }
    f32x4 sum = {};
#pragma unroll
    for (int n = 0; n < 8; ++n)
#pragma unroll
      for (int r = 0; r < 4; ++r) {
        float e = exp2f((s[n][r] - mxv[r]) * 1.44269504f);
        s[n][r] = e;
        sum[r] += e;
      }
    float inv_[4];
#pragma unroll
    for (int r = 0; r < 4; ++r) {
      float t = sum[r];
      t += __shfl_xor(t, 1);
      t += __shfl_xor(t, 2);
      t += __shfl_xor(t, 4);
      t += __shfl_xor(t, 8);
      inv_[r] = __builtin_amdgcn_rcpf(t);
    }

    // probs (fp32, from registers) + P (bf16) to wave-private band
    const size_t pbase = ((size_t)h * CC + c) << 14;
#pragma unroll
    for (int n = 0; n < 8; ++n)
#pragma unroll
      for (int r = 0; r < 4; ++r) {
        float pv = s[n][r] * inv_[r];
        int i = (w << 4) + (lg << 2) + r;
        int j = (n << 4) + lr;
        probs[pbase + (size_t)i * 128 + j] = pv;
        ps[i * 136 + j] = f2bf(pv);
      }

    // PV (no barrier: P band wave-private, V^T[cur] staged pre-barrier)
    f32x4 o[4] = {};
#pragma unroll
    for (int kk = 0; kk < 4; ++kk) {
      bf16x8 pa = *(const bf16x8*)&ps[((w << 4) + lr) * 136 + kk * 32 + (lg << 3)];
      bf16x8 vbr[4];
#pragma unroll
      for (int n = 0; n < 4; ++n) {
        int d = (n << 4) + lr;
        int jb = (kk * 32 + (lg << 3)) ^ ((((d >> 3) & 7)) << 3);
        vbr[n] = *(const bf16x8*)&vtc[d * 136 + jb];
      }
#pragma unroll
      for (int n = 0; n < 4; ++n)
        o[n] = __builtin_amdgcn_mfma_f32_16x16x32_bf16(pa, vbr[n], o[n], 0, 0, 0);
    }

    // write prefetched V into the idle buffer (swizzled); roll Q
    if (pf) {
      unsigned short* vtn = sm + 16384 + (cur ^ 1) * 8704;
      int jx0 = j0 ^ (dblk << 3);
      int jx1 = (64 + j0) ^ (dblk << 3);
#pragma unroll
      for (int u = 0; u < 8; ++u) vtn[(d00 + u) * 136 + jx0] = (unsigned short)vr0[u];
#pragma unroll
      for (int u = 0; u < 8; ++u) vtn[(d00 + u) * 136 + jx1] = (unsigned short)vr1[u];
      qf0 = qn0; qf1 = qn1;
    }

    // ctx via wave-private bounce (reuse own P band, dead after PV)
    unsigned short* bandc = ps + ((w << 4) * 136);
#pragma unroll
    for (int n = 0; n < 4; ++n)
#pragma unroll
      for (int r = 0; r < 4; ++r)
        bandc[((lg << 2) + r) * 64 + (n << 4) + lr] = f2bf(o[n][r]);
#pragma unroll
    for (int q = 0; q < 2; ++q) {
      int fl = q * 64 + lane;
      int iL = fl >> 3, d8 = fl & 7;
      *(u16x8*)(ctx + ((size_t)c * 128 + (w << 4) + iL) * EE + h * 64 + d8 * 8) =
          *(const u16x8*)(bandc + iL * 64 + d8 * 8);
    }

    __syncthreads();
    cur ^= 1;
  }
}

extern "C" void kernel_launch(void* const* d_in, const int* in_sizes, int n_in,
                              void* d_out, int out_size, void* d_ws, size_t ws_size,
                              hipStream_t stream) {
  const float* x = (const float*)d_in[0];
  const unsigned char* pm = (const unsigned char*)d_in[1];
  const float* Wq = (const float*)d_in[2];
  const float* bq = (const float*)d_in[3];
  const float* Wk = (const float*)d_in[4];
  const float* bk = (const float*)d_in[5];
  const float* Wv = (const float*)d_in[6];
  const float* bv = (const float*)d_in[7];
  const float* Wo = (const float*)d_in[8];
  const float* bo = (const float*)d_in[9];

  unsigned short* ws = (unsigned short*)d_ws;
  unsigned short* xb = ws;                       // 25165824 (x_bf16, later ctx c-major)
  unsigned short* qkv = xb + 25165824;           // 3 x 25165824 ([c][h][i][d] per matrix)
  unsigned short* wcast = qkv + 75497472;        // 4 x 589824 (Wq|Wk|Wv|Wo)

  float* outp = (float*)d_out;
  float* probs = outp + 25165824;

  cast_all<<<13440, 256, 0, stream>>>(x, Wq, Wk, Wv, Wo, xb, wcast);
  gemm256<1><<<1152, 512, 0, stream>>>(xb, wcast, (void*)qkv, bq, bk, bv);
  attn_col<<<CC, 512, 0, stream>>>(qkv, qkv + 25165824, qkv + 50331648,
                                   pm, probs, xb /*ctx c-major*/);
  gemm256<0><<<384, 512, 0, stream>>>(xb, wcast + 1769472, (void*)outp, bo,
                                      nullptr, nullptr);
}